// Round 1
// baseline (1221.861 us; speedup 1.0000x reference)
//
#include <hip/hip_runtime.h>
#include <hip/hip_bf16.h>

// MultiHeadElman: T=4096 sequential steps of h = softsign(R@h + Wx@x_t + bias)
// per (b,h) chain. 256 independent chains -> one 64-lane wave each.
// Lane (i = lane&31, p = lane>>5) owns output row i, j-slice [16p, 16p+16).

constexpr int T_STEPS = 4096;
constexpr int B_SZ    = 4;
constexpr int D_SZ    = 2048;
constexpr int H_SZ    = 64;
constexpr int HD      = 32;

__global__ __launch_bounds__(64, 1)
void elman_scan(const float* __restrict__ x,
                const float* __restrict__ h0,
                const float* __restrict__ R,
                const float* __restrict__ Wx,
                const float* __restrict__ bias,
                float* __restrict__ out)
{
    const int lane = threadIdx.x & 63;
    const int i    = lane & (HD - 1);   // output row 0..31
    const int p    = lane >> 5;         // j-half 0/1
    const int h    = blockIdx.x & (H_SZ - 1);
    const int b    = blockIdx.x >> 6;

    // --- one-time loads: R/Wx row slices into registers ---
    float r[16], w[16], hj[16];
    {
        const float4* Rp = (const float4*)(R  + ((h * HD + i) * HD + 16 * p));
        const float4* Wp = (const float4*)(Wx + ((h * HD + i) * HD + 16 * p));
#pragma unroll
        for (int q = 0; q < 4; ++q) {
            float4 rv = Rp[q], wv = Wp[q];
            r[4*q+0] = rv.x; r[4*q+1] = rv.y; r[4*q+2] = rv.z; r[4*q+3] = rv.w;
            w[4*q+0] = wv.x; w[4*q+1] = wv.y; w[4*q+2] = wv.z; w[4*q+3] = wv.w;
        }
    }
    const float bi = bias[h * HD + i];

    // initial hidden state slice h0[b][h][16p + jj]
    {
        const float4* hp = (const float4*)(h0 + ((b * H_SZ + h) * HD + 16 * p));
#pragma unroll
        for (int q = 0; q < 4; ++q) {
            float4 hv = hp[q];
            hj[4*q+0] = hv.x; hj[4*q+1] = hv.y; hj[4*q+2] = hv.z; hj[4*q+3] = hv.w;
        }
    }

    // two replicated copies of h (64 floats) so both halves read conflict-free
    __shared__ __align__(16) float hs[64];

    const long strideT = (long)B_SZ * D_SZ;       // 8192 floats per t
    const float* xp = x   + ((long)b * D_SZ + h * HD + 16 * p);
    float*       op = out + ((long)b * D_SZ + h * HD + i);

    float4 xc[4], xn[4];
#pragma unroll
    for (int q = 0; q < 4; ++q) { xc[q] = ((const float4*)xp)[q]; xn[q] = xc[q]; }

    float hn = 0.0f;

    for (int t = 0; t < T_STEPS; ++t) {
        // prefetch next step's x slice (off critical chain)
        if (t + 1 < T_STEPS) {
            const float4* nx = (const float4*)(xp + strideT);
#pragma unroll
            for (int q = 0; q < 4; ++q) xn[q] = nx[q];
        }

        float xa[16];
#pragma unroll
        for (int q = 0; q < 4; ++q) {
            xa[4*q+0] = xc[q].x; xa[4*q+1] = xc[q].y;
            xa[4*q+2] = xc[q].z; xa[4*q+3] = xc[q].w;
        }

        // 4-way split accumulation: Wx.x partial first (independent of h),
        // then R.h partial on top.
        float a0 = w[0] * xa[0];
        float a1 = w[1] * xa[1];
        float a2 = w[2] * xa[2];
        float a3 = w[3] * xa[3];
#pragma unroll
        for (int q = 1; q < 4; ++q) {
            a0 = fmaf(w[4*q+0], xa[4*q+0], a0);
            a1 = fmaf(w[4*q+1], xa[4*q+1], a1);
            a2 = fmaf(w[4*q+2], xa[4*q+2], a2);
            a3 = fmaf(w[4*q+3], xa[4*q+3], a3);
        }
#pragma unroll
        for (int q = 0; q < 4; ++q) {
            a0 = fmaf(r[4*q+0], hj[4*q+0], a0);
            a1 = fmaf(r[4*q+1], hj[4*q+1], a1);
            a2 = fmaf(r[4*q+2], hj[4*q+2], a2);
            a3 = fmaf(r[4*q+3], hj[4*q+3], a3);
        }
        float acc = (a0 + a1) + (a2 + a3);
        acc += __shfl_xor(acc, 32, 64);           // combine the two j-halves
        float pre = acc + bi;
        // softsign: pre / (1 + |pre|); v_rcp_f32 is ~1 ulp, recurrence is
        // contractive -> error ~1e-6, threshold is 1.7e-2.
        hn = pre * __builtin_amdgcn_rcpf(1.0f + fabsf(pre));

        // stream output (lanes 0..31 hold the canonical copy)
        if (lane < HD) op[0] = hn;

        // redistribute h for next step: write 2 replicated copies, read slice
        hs[p * 32 + i] = hn;
        __syncthreads();   // single wave: compiles to lgkmcnt wait (+ cheap barrier)
        {
            const float4* hv = (const float4*)(&hs[p * 48]); // p=0 -> h[0..15], p=1 -> h[16..31]
#pragma unroll
            for (int q = 0; q < 4; ++q) {
                float4 t4 = hv[q];
                hj[4*q+0] = t4.x; hj[4*q+1] = t4.y;
                hj[4*q+2] = t4.z; hj[4*q+3] = t4.w;
            }
        }

#pragma unroll
        for (int q = 0; q < 4; ++q) xc[q] = xn[q];
        xp += strideT;
        op += strideT;
    }

    // h_final: concatenated after ys in d_out
    if (lane < HD) {
        out[(long)T_STEPS * strideT + (b * H_SZ + h) * HD + i] = hn;
    }
}

extern "C" void kernel_launch(void* const* d_in, const int* in_sizes, int n_in,
                              void* d_out, int out_size, void* d_ws, size_t ws_size,
                              hipStream_t stream) {
    const float* x    = (const float*)d_in[0];
    const float* h0   = (const float*)d_in[1];
    const float* R    = (const float*)d_in[2];
    const float* Wx   = (const float*)d_in[3];
    const float* bias = (const float*)d_in[4];
    float* out = (float*)d_out;

    elman_scan<<<dim3(B_SZ * H_SZ), dim3(64), 0, stream>>>(x, h0, R, Wx, bias, out);
}

// Round 2
// 1060.128 us; speedup vs baseline: 1.1526x; 1.1526x over previous
//
#include <hip/hip_runtime.h>
#include <hip/hip_bf16.h>

// MultiHeadElman: T=4096 sequential steps of h = softsign(R@h + Wx@x_t + bias)
// per (b,h) chain. 256 independent chains -> one 64-lane wave each.
// Lane (i = lane&31, p = lane>>5) owns output row i, j-slice [16p, 16p+16).
//
// R2: deep x prefetch (depth 8, rotating register buffer, loop unrolled x8)
// to hide the ~900-cycle HBM load latency that dominated R1 (987 cy/step).

constexpr int T_STEPS = 4096;
constexpr int B_SZ    = 4;
constexpr int D_SZ    = 2048;
constexpr int H_SZ    = 64;
constexpr int HD      = 32;
constexpr int PF      = 8;     // prefetch depth (T_STEPS % PF == 0)

__global__ __launch_bounds__(64, 1)
void elman_scan(const float* __restrict__ x,
                const float* __restrict__ h0,
                const float* __restrict__ R,
                const float* __restrict__ Wx,
                const float* __restrict__ bias,
                float* __restrict__ out)
{
    const int lane = threadIdx.x & 63;
    const int i    = lane & (HD - 1);   // output row 0..31
    const int p    = lane >> 5;         // j-half 0/1
    const int h    = blockIdx.x & (H_SZ - 1);
    const int b    = blockIdx.x >> 6;

    // --- one-time loads: R/Wx row slices into registers ---
    float r[16], w[16], hj[16];
    {
        const float4* Rp = (const float4*)(R  + ((h * HD + i) * HD + 16 * p));
        const float4* Wp = (const float4*)(Wx + ((h * HD + i) * HD + 16 * p));
#pragma unroll
        for (int q = 0; q < 4; ++q) {
            float4 rv = Rp[q], wv = Wp[q];
            r[4*q+0] = rv.x; r[4*q+1] = rv.y; r[4*q+2] = rv.z; r[4*q+3] = rv.w;
            w[4*q+0] = wv.x; w[4*q+1] = wv.y; w[4*q+2] = wv.z; w[4*q+3] = wv.w;
        }
    }
    const float bi = bias[h * HD + i];

    // initial hidden state slice h0[b][h][16p + jj]
    {
        const float4* hp = (const float4*)(h0 + ((b * H_SZ + h) * HD + 16 * p));
#pragma unroll
        for (int q = 0; q < 4; ++q) {
            float4 hv = hp[q];
            hj[4*q+0] = hv.x; hj[4*q+1] = hv.y; hj[4*q+2] = hv.z; hj[4*q+3] = hv.w;
        }
    }

    // replicated h copies: hs[0..31] and hs[32..63] both hold h[0..31]
    __shared__ __align__(16) float hs[64];

    const long strideT = (long)B_SZ * D_SZ;       // 8192 floats per t
    const float* xp = x   + ((long)b * D_SZ + h * HD + 16 * p);
    float*       op = out + ((long)b * D_SZ + h * HD + i);

    // --- prefetch buffer: PF steps in flight ---
    float4 xb[PF][4];
#pragma unroll
    for (int k = 0; k < PF; ++k) {
        const float4* src = (const float4*)(xp + (long)k * strideT);
#pragma unroll
        for (int q = 0; q < 4; ++q) xb[k][q] = src[q];
    }

    float hn = 0.0f;

    for (int tb = 0; tb < T_STEPS; tb += PF) {
        const bool do_pf = (tb + PF < T_STEPS);   // uniform per block of PF
#pragma unroll
        for (int k = 0; k < PF; ++k) {
            // consume slot k (waits on the load issued PF steps ago)
            float xa[16];
#pragma unroll
            for (int q = 0; q < 4; ++q) {
                xa[4*q+0] = xb[k][q].x; xa[4*q+1] = xb[k][q].y;
                xa[4*q+2] = xb[k][q].z; xa[4*q+3] = xb[k][q].w;
            }
            // refill slot k for step (tb + k + PF)
            if (do_pf) {
                const float4* src = (const float4*)(xp + (long)PF * strideT);
#pragma unroll
                for (int q = 0; q < 4; ++q) xb[k][q] = src[q];
            }

            // Wx.x partial first (independent of h), then R.h on top.
            float a0 = w[0] * xa[0];
            float a1 = w[1] * xa[1];
            float a2 = w[2] * xa[2];
            float a3 = w[3] * xa[3];
#pragma unroll
            for (int q = 1; q < 4; ++q) {
                a0 = fmaf(w[4*q+0], xa[4*q+0], a0);
                a1 = fmaf(w[4*q+1], xa[4*q+1], a1);
                a2 = fmaf(w[4*q+2], xa[4*q+2], a2);
                a3 = fmaf(w[4*q+3], xa[4*q+3], a3);
            }
#pragma unroll
            for (int q = 0; q < 4; ++q) {
                a0 = fmaf(r[4*q+0], hj[4*q+0], a0);
                a1 = fmaf(r[4*q+1], hj[4*q+1], a1);
                a2 = fmaf(r[4*q+2], hj[4*q+2], a2);
                a3 = fmaf(r[4*q+3], hj[4*q+3], a3);
            }
            float acc = (a0 + a1) + (a2 + a3);
            acc += __shfl_xor(acc, 32, 64);       // combine the two j-halves
            float pre = acc + bi;
            // softsign via v_rcp_f32 (~1 ulp; recurrence is contractive)
            hn = pre * __builtin_amdgcn_rcpf(1.0f + fabsf(pre));

            // stream output (lanes 0..31 hold the canonical copy)
            if (lane < HD) op[0] = hn;

            // redistribute h: write 2 replicated copies, read own slice back
            hs[p * 32 + i] = hn;
            __syncthreads();   // 1 wave: lgkmcnt drain + trivial barrier
            {
                const float4* hv = (const float4*)(&hs[p * 48]); // p=0->h[0..15], p=1->h[16..31]
#pragma unroll
                for (int q = 0; q < 4; ++q) {
                    float4 t4 = hv[q];
                    hj[4*q+0] = t4.x; hj[4*q+1] = t4.y;
                    hj[4*q+2] = t4.z; hj[4*q+3] = t4.w;
                }
            }

            xp += strideT;
            op += strideT;
        }
    }

    // h_final: concatenated after ys in d_out
    if (lane < HD) {
        out[(long)T_STEPS * strideT + (b * H_SZ + h) * HD + i] = hn;
    }
}

extern "C" void kernel_launch(void* const* d_in, const int* in_sizes, int n_in,
                              void* d_out, int out_size, void* d_ws, size_t ws_size,
                              hipStream_t stream) {
    const float* x    = (const float*)d_in[0];
    const float* h0   = (const float*)d_in[1];
    const float* R    = (const float*)d_in[2];
    const float* Wx   = (const float*)d_in[3];
    const float* bias = (const float*)d_in[4];
    float* out = (float*)d_out;

    elman_scan<<<dim3(B_SZ * H_SZ), dim3(64), 0, stream>>>(x, h0, R, Wx, bias, out);
}